// Round 7
// baseline (347.331 us; speedup 1.0000x reference)
//
#include <hip/hip_runtime.h>
#include <hip/hip_bf16.h>

// VectorQuantizer on MI355X — R14:
//  (a) vq_main at FULL occupancy: 16 tokens/wave, 128 tokens/block -> 1024
//      blocks = 4 blocks/CU = 32 waves/CU (was grid-capped at 16). R13 showed
//      the K-loop is fetch-latency-bound with all pipes <25% busy and
//      occupancy 34% — the generic TLP lever applies. Depth-1 register
//      prefetch of next group's pk fragments decouples load->MFMA serial
//      dependence within an iteration. __launch_bounds__(512,8) pins VGPR<=64.
//  (b) dw: dimension-partitioned dense scatter (R12, unchanged).
// Inputs (fp32): z[NT,64], codebook[K,64], cluster_size[K], ema_w[K,64]
// d_out (fp32): quantized[NT*64] | indices[NT] | loss[1] | new_codebook[K*64] |
//   new_cluster_size[K] | new_ema_w[K*64]
// ws dwords: cnt[K](int) | cnormp[K] | loss | n | pad | pk[K*32] |
//   partial[nchunks][K*64]

#define DECAY 0.99f
#define OMD   0.01f
#define EPSV  1e-5f
#define BIASF 192.0f    // folded into MFMA acc init: score' = 192 + z.c - |c|^2/2 > 0

typedef __attribute__((ext_vector_type(8))) __bf16 bf16x8;
typedef __attribute__((ext_vector_type(4))) float  float4v;

static __device__ __forceinline__ bf16x8 cvt8(float4v a, float4v b) {
    bf16x8 r;
    r[0] = (__bf16)a[0]; r[1] = (__bf16)a[1]; r[2] = (__bf16)a[2]; r[3] = (__bf16)a[3];
    r[4] = (__bf16)b[0]; r[5] = (__bf16)b[1]; r[6] = (__bf16)b[2]; r[7] = (__bf16)b[3];
    return r;
}

// key low 8 bits = per-lane candidate number iter = (tt<<2)|r  (K<=1024)
static __device__ __forceinline__ int dec_idx(unsigned key, int quad) {
    int iter = key & 255;
    return ((iter >> 6) << 8) + (((iter >> 2) & 15) << 4) + (quad << 2) + (iter & 3);
}

// Grid covers K*4 threads (one per (t-group, lane) fragment pair) + K cnorm.
__global__ void vq_prep(const float* __restrict__ cb,
                        float* __restrict__ wsf, int* __restrict__ wsi,
                        unsigned short* __restrict__ pk,
                        int K, int NT) {
    int t = blockIdx.x * 256 + threadIdx.x;
    if (t < K) {
        wsi[t] = 0;                               // cnt
        const float4v* cp = (const float4v*)(cb + (size_t)t * 64);
        float s = 0.f;
        #pragma unroll
        for (int i = 0; i < 16; ++i) {
            float4v v = cp[i];
            s += v[0] * v[0] + v[1] * v[1] + v[2] * v[2] + v[3] * v[3];
        }
        wsf[K + t] = BIASF - 0.5f * s;            // cnormp
    }
    if (t < K * 4) {                              // fragment packing
        int tg  = t >> 6;                         // t-group (16 codes)
        int l   = t & 63;                         // lane
        int col = l & 15, q = l >> 4;
        int code = tg * 16 + col;
        bf16x8 a0, a1;
        if (code < K) {
            const float* s0 = cb + (size_t)code * 64 + q * 8;
            a0 = cvt8(*(const float4v*)(s0),      *(const float4v*)(s0 + 4));
            a1 = cvt8(*(const float4v*)(s0 + 32), *(const float4v*)(s0 + 36));
        } else {
            #pragma unroll
            for (int j = 0; j < 8; ++j) { a0[j] = (__bf16)0.f; a1[j] = (__bf16)0.f; }
        }
        bf16x8* dst = (bf16x8*)(pk + (size_t)t * 16);
        dst[0] = a0;                              // 16B
        dst[1] = a1;                              // 16B
    }
    if (t == 0) wsf[2 * K] = 0.f;                 // loss
}

// 512 threads = 8 waves; 128 tokens/block (16/wave); barrier-free K-loop;
// 1024 blocks -> 4 blocks/CU -> 32 waves/CU.
__launch_bounds__(512, 8)
__global__ void vq_main(const float* __restrict__ z,
                        const float* __restrict__ cb,
                        const unsigned short* __restrict__ pk,
                        float* __restrict__ wsf, int* __restrict__ wsi,
                        float* __restrict__ out,
                        int NT, int K) {
    __shared__ int hist[1024];

    const int tid  = threadIdx.x;
    const int lane = tid & 63;
    const int col  = lane & 15;
    const int quad = lane >> 4;
    const int wtok0 = blockIdx.x * 128 + (tid >> 6) * 16;
    const float* cnormp = wsf + K;
    float* lossp = wsf + 2 * K;
    const bool smallK = (K <= 1024);

    for (int i = tid; i < 1024; i += 512) hist[i] = 0;

    bf16x8 bf0, bf1;
    {
        int tok = wtok0 + col;
        if (tok >= NT) tok = NT - 1;
        const float* zp = z + (size_t)tok * 64 + quad * 8;
        bf0 = cvt8(*(const float4v*)(zp),      *(const float4v*)(zp + 4));
        bf1 = cvt8(*(const float4v*)(zp + 32), *(const float4v*)(zp + 36));
    }

    unsigned k1 = 0u, k2 = 0u;
    const unsigned kmask = 0xFFFFFF00u;
    const int ngrp = (K + 15) >> 4;               // 16-code groups (<=64)
    const unsigned short* pl = pk + lane * 16;    // this lane's fragment column

    // depth-1 rotating prefetch
    bf16x8 a0 = ((const bf16x8*)pl)[0];
    bf16x8 a1 = ((const bf16x8*)pl)[1];
    float4v cni = *(const float4v*)(cnormp + quad * 4);

    #pragma unroll 2
    for (int tt = 0; tt < ngrp; ++tt) {
        const int ttn = (tt + 1 < ngrp) ? tt + 1 : tt;
        const bf16x8* f = (const bf16x8*)(pl + (size_t)ttn * 1024);
        bf16x8 n0 = f[0];
        bf16x8 n1 = f[1];
        float4v cnn = *(const float4v*)(cnormp + ttn * 16 + quad * 4);

        float4v acc = cni;                        // = BIAS - |c|^2/2
        acc = __builtin_amdgcn_mfma_f32_16x16x32_bf16(a0, bf0, acc, 0, 0, 0);
        acc = __builtin_amdgcn_mfma_f32_16x16x32_bf16(a1, bf1, acc, 0, 0, 0);
        const int iterbase = tt << 2;
        #pragma unroll
        for (int r = 0; r < 4; ++r) {
            unsigned kb = (__float_as_uint(acc[r]) & kmask) | (unsigned)(iterbase + r);
            unsigned lo = k2 > kb ? k2 : kb;
            k2 = k1 < lo ? k1 : lo;
            k1 = k1 > kb ? k1 : kb;
        }
        a0 = n0; a1 = n1; cni = cnn;
    }

    // Cooperative exact refine (R9): 4 quad-lanes per token jointly rerank the
    // token's 8 candidates in fp64; each lane covers a 16-dim slice.
    int ibst;
    {
        int tok = wtok0 + col;
        if (tok >= NT) tok = NT - 1;
        int ia = dec_idx(k1, quad);
        int ib = dec_idx(k2, quad);
        int cand[8];
        #pragma unroll
        for (int q = 0; q < 4; ++q) {
            cand[2 * q]     = __shfl(ia, q * 16 + col, 64);
            cand[2 * q + 1] = __shfl(ib, q * 16 + col, 64);
        }
        const float* zr = z + (size_t)tok * 64 + quad * 16;
        float4v zv0 = *(const float4v*)(zr);
        float4v zv1 = *(const float4v*)(zr + 4);
        float4v zv2 = *(const float4v*)(zr + 8);
        float4v zv3 = *(const float4v*)(zr + 12);
        double ps[8];
        #pragma unroll
        for (int s = 0; s < 8; ++s) {
            int cc = (cand[s] < K) ? cand[s] : 0;
            const float* cr = cb + (size_t)cc * 64 + quad * 16;
            float4v c0 = *(const float4v*)(cr);
            float4v c1 = *(const float4v*)(cr + 4);
            float4v c2 = *(const float4v*)(cr + 8);
            float4v c3 = *(const float4v*)(cr + 12);
            double a = 0.0;
            #pragma unroll
            for (int j = 0; j < 4; ++j) {
                double e0 = (double)zv0[j] - (double)c0[j];
                double e1 = (double)zv1[j] - (double)c1[j];
                double e2 = (double)zv2[j] - (double)c2[j];
                double e3 = (double)zv3[j] - (double)c3[j];
                a = fma(e0, e0, a); a = fma(e1, e1, a);
                a = fma(e2, e2, a); a = fma(e3, e3, a);
            }
            ps[s] = (cand[s] < K) ? a : 1.0e300;
        }
        #pragma unroll
        for (int s = 0; s < 8; ++s) {
            ps[s] += __shfl_xor(ps[s], 16, 64);
            ps[s] += __shfl_xor(ps[s], 32, 64);
        }
        double bs = ps[0]; int bi = cand[0];
        #pragma unroll
        for (int s = 1; s < 8; ++s) {
            if (ps[s] < bs || (ps[s] == bs && cand[s] < bi)) { bs = ps[s]; bi = cand[s]; }
        }
        ibst = bi;
    }

    const size_t off_idx = (size_t)NT * 64;
    __syncthreads();                              // hist zero-init visible

    if (lane < 16) {
        int tk = wtok0 + lane;
        if (tk < NT) {
            out[off_idx + tk] = (float)ibst;      // lane==col here: own token
            if (smallK) atomicAdd(&hist[ibst], 1);
            else        atomicAdd(&wsi[ibst], 1);
        }
    }

    // Epilogue: quantized write + commitment loss.
    float lsum = 0.f;
    #pragma unroll
    for (int i = 0; i < 4; ++i) {
        int tw  = i * 4 + quad;                   // 0..15
        int idx = __shfl(ibst, tw, 64);
        int token = wtok0 + tw;
        if (token < NT) {
            int d4 = col * 4;
            float4v zf = *(const float4v*)(z  + (size_t)token * 64 + d4);
            float4v qf = *(const float4v*)(cb + (size_t)idx   * 64 + d4);
            *(float4v*)(out + (size_t)token * 64 + d4) = qf;
            float e0 = zf[0] - qf[0], e1 = zf[1] - qf[1];
            float e2 = zf[2] - qf[2], e3 = zf[3] - qf[3];
            lsum += e0 * e0 + e1 * e1 + e2 * e2 + e3 * e3;
        }
    }
    #pragma unroll
    for (int off = 1; off < 64; off <<= 1) lsum += __shfl_xor(lsum, off, 64);
    if (lane == 0) atomicAdd(lossp, lsum);

    __syncthreads();
    if (smallK) {
        for (int k = tid; k < K; k += 512) {
            int c = hist[k];
            if (c) atomicAdd(&wsi[k], c);
        }
    }
}

// Dimension-partitioned dw scatter (R12, unchanged). Block (chunk, g) owns
// dims [g*16,g*16+16) of ALL K codes; LDS acc[K][16] (64KB). Fully dense —
// no ballot/shfl chains. Exclusive writeout. Block 0 folds the nsum duty.
__launch_bounds__(512)
__global__ void vq_dwred(const float* __restrict__ z,
                         const float* __restrict__ out_idx,
                         const float* __restrict__ cs,
                         float* __restrict__ wsf, const int* __restrict__ wsi,
                         float* __restrict__ partial,
                         float* __restrict__ out,
                         int NT, int K, int nchunks) {
    extern __shared__ float acc[];               // K*16 floats
    __shared__ float red[8];

    const int tid   = threadIdx.x;
    const int lane  = tid & 63;
    const int wave  = tid >> 6;                  // 8 waves
    const int chunk = blockIdx.x >> 2;
    const int g     = blockIdx.x & 3;
    const int tsub  = lane >> 4;
    const int d     = lane & 15;
    const size_t KD = (size_t)K * 64;

    for (int i = tid; i < K * 16; i += 512) acc[i] = 0.f;

    if (blockIdx.x == 0) {
        // folded nsum duty (cnt ready: vq_main completed before this kernel)
        float part = 0.f;
        for (int k = tid; k < K; k += 512)
            part += DECAY * cs[k] + OMD * (float)wsi[k];
        #pragma unroll
        for (int off = 1; off < 64; off <<= 1) part += __shfl_xor(part, off, 64);
        if (lane == 0) red[wave] = part;
        __syncthreads();
        if (tid == 0) {
            float nn = 0.f;
            #pragma unroll
            for (int i = 0; i < 8; ++i) nn += red[i];
            wsf[2 * K + 1] = nn;                                  // n
            out[(size_t)NT * 64 + NT] = wsf[2 * K] / ((float)NT * 64.0f);
        }
    }
    __syncthreads();

    const int C  = (NT + nchunks - 1) / nchunks;
    const int T0 = chunk * C;
    const int T1 = (T0 + C < NT) ? (T0 + C) : NT;
    const float* zs = z + g * 16 + d;

    #pragma unroll 4
    for (int t = T0 + wave * 4 + tsub; t < T1; t += 32) {
        float v   = zs[(size_t)t * 64];
        int  code = (int)out_idx[t];
        atomicAdd(&acc[code * 16 + d], v);
    }
    __syncthreads();

    // exclusive writeout: dims [g*16, g*16+16) of partial[chunk]
    float* pb = partial + (size_t)chunk * KD + g * 16;
    for (int i = tid; i < K * 16; i += 512) {
        int k = i >> 4, dd = i & 15;
        pb[(size_t)k * 64 + dd] = acc[i];
    }
}

// Final: sum chunk partials -> new_ema_w, new_codebook, new_cluster_size.
__global__ void vq_final(const float* __restrict__ cs,
                         const float* __restrict__ ema,
                         const float* __restrict__ wsf,
                         const int* __restrict__ wsi,
                         const float* __restrict__ partial,
                         float* __restrict__ out, int NT, int K, int S) {
    const int KD = K * 64;
    int t = blockIdx.x * 256 + threadIdx.x;
    if (t >= KD) return;
    const int k = t >> 6;
    const float n = wsf[2 * K + 1];
    float dsum = 0.f;
    #pragma unroll 4
    for (int s = 0; s < S; ++s) dsum += partial[(size_t)s * KD + t];
    const float dw = DECAY * ema[t] + OMD * dsum;
    const float ncs = DECAY * cs[k] + OMD * (float)wsi[k];
    const float csn = (ncs + EPSV) / (n + (float)K * EPSV) * n;
    const size_t off_cb  = (size_t)NT * 64 + NT + 1;
    const size_t off_cs  = off_cb + (size_t)KD;
    const size_t off_ema = off_cs + K;
    out[off_cb  + t] = dw / csn;
    out[off_ema + t] = dw;
    if ((t & 63) == 0) out[off_cs + k] = ncs;
}

extern "C" void kernel_launch(void* const* d_in, const int* in_sizes, int n_in,
                              void* d_out, int out_size, void* d_ws, size_t ws_size,
                              hipStream_t stream) {
    const float* z   = (const float*)d_in[0];
    const float* cb  = (const float*)d_in[1];
    const float* cs  = (const float*)d_in[2];
    const float* ema = (const float*)d_in[3];
    float* out = (float*)d_out;
    float* wsf = (float*)d_ws;
    int*   wsi = (int*)d_ws;

    const int NT = in_sizes[0] / 64;
    const int K  = in_sizes[2];
    const int KD = K * 64;

    // ws layout (dwords): [0,K) cnt | [K,2K) cnormp | 2K loss | 2K+1 n |
    //   off_pk: pk (K*32 dwords, 16B-aligned) | off_pa: partials
    const size_t off_pk = (((size_t)2 * K + 2) + 7) & ~(size_t)7;
    const size_t off_pa = off_pk + (size_t)K * 32;

    size_t avail = ws_size / 4;                  // dwords
    int nchunks = 128;
    while (nchunks > 1 && off_pa + (size_t)nchunks * KD > avail)
        nchunks >>= 1;

    unsigned short* pk = (unsigned short*)(wsf + off_pk);
    float* partial = wsf + off_pa;
    const size_t dwlds = (size_t)K * 16 * sizeof(float);   // 64KB @ K=1024

    vq_prep<<<(K * 4 + 255) / 256, 256, 0, stream>>>(cb, wsf, wsi, pk, K, NT);
    vq_main<<<(NT + 127) / 128, 512, 0, stream>>>(z, cb, pk, wsf, wsi, out, NT, K);
    vq_dwred<<<nchunks * 4, 512, dwlds, stream>>>(
        z, out + (size_t)NT * 64, cs, wsf, wsi, partial, out, NT, K, nchunks);
    vq_final<<<(KD + 255) / 256, 256, 0, stream>>>(cs, ema, wsf, wsi, partial,
                                                   out, NT, K, nchunks);
}

// Round 8
// 339.232 us; speedup vs baseline: 1.0239x; 1.0239x over previous
//
#include <hip/hip_runtime.h>
#include <hip/hip_bf16.h>

// VectorQuantizer on MI355X — R15:
//  (a) vq_main: R14's 16-tok/wave 1024-block grid, but WITHOUT the
//      launch_bounds min-wave hint (R14's (512,8) forced VGPR=32 on the
//      unified VGPR/AGPR file -> ~160MB scratch spill traffic, 203us).
//      Slim refine (incremental best, no ps[8] array) keeps VGPR<=64 so
//      HW reaches 8 waves/SIMD naturally. K-loop barriers every 8 groups
//      make the block's 8 waves share one 16KB pk window in L1 instead of
//      8 independent 128KB streams (L1 thrash -> every load L2, 94% stall).
//  (b) dw: dimension-partitioned dense scatter (R12, unchanged).
//  (c) vq_final: 8-accumulator interleaved dsum (8 outstanding loads).
// Inputs (fp32): z[NT,64], codebook[K,64], cluster_size[K], ema_w[K,64]
// d_out (fp32): quantized[NT*64] | indices[NT] | loss[1] | new_codebook[K*64] |
//   new_cluster_size[K] | new_ema_w[K*64]
// ws dwords: cnt[K](int) | cnormp[K] | loss | n | pad | pk[K*32] |
//   partial[nchunks][K*64]

#define DECAY 0.99f
#define OMD   0.01f
#define EPSV  1e-5f
#define BIASF 192.0f    // folded into MFMA acc init: score' = 192 + z.c - |c|^2/2 > 0

typedef __attribute__((ext_vector_type(8))) __bf16 bf16x8;
typedef __attribute__((ext_vector_type(4))) float  float4v;

static __device__ __forceinline__ bf16x8 cvt8(float4v a, float4v b) {
    bf16x8 r;
    r[0] = (__bf16)a[0]; r[1] = (__bf16)a[1]; r[2] = (__bf16)a[2]; r[3] = (__bf16)a[3];
    r[4] = (__bf16)b[0]; r[5] = (__bf16)b[1]; r[6] = (__bf16)b[2]; r[7] = (__bf16)b[3];
    return r;
}

// key low 8 bits = per-lane candidate number iter = (tt<<2)|r  (K<=1024)
static __device__ __forceinline__ int dec_idx(unsigned key, int quad) {
    int iter = key & 255;
    return ((iter >> 6) << 8) + (((iter >> 2) & 15) << 4) + (quad << 2) + (iter & 3);
}

// Grid covers K*4 threads (one per (t-group, lane) fragment pair) + K cnorm.
__global__ void vq_prep(const float* __restrict__ cb,
                        float* __restrict__ wsf, int* __restrict__ wsi,
                        unsigned short* __restrict__ pk,
                        int K, int NT) {
    int t = blockIdx.x * 256 + threadIdx.x;
    if (t < K) {
        wsi[t] = 0;                               // cnt
        const float4v* cp = (const float4v*)(cb + (size_t)t * 64);
        float s = 0.f;
        #pragma unroll
        for (int i = 0; i < 16; ++i) {
            float4v v = cp[i];
            s += v[0] * v[0] + v[1] * v[1] + v[2] * v[2] + v[3] * v[3];
        }
        wsf[K + t] = BIASF - 0.5f * s;            // cnormp
    }
    if (t < K * 4) {                              // fragment packing
        int tg  = t >> 6;                         // t-group (16 codes)
        int l   = t & 63;                         // lane
        int col = l & 15, q = l >> 4;
        int code = tg * 16 + col;
        bf16x8 a0, a1;
        if (code < K) {
            const float* s0 = cb + (size_t)code * 64 + q * 8;
            a0 = cvt8(*(const float4v*)(s0),      *(const float4v*)(s0 + 4));
            a1 = cvt8(*(const float4v*)(s0 + 32), *(const float4v*)(s0 + 36));
        } else {
            #pragma unroll
            for (int j = 0; j < 8; ++j) { a0[j] = (__bf16)0.f; a1[j] = (__bf16)0.f; }
        }
        bf16x8* dst = (bf16x8*)(pk + (size_t)t * 16);
        dst[0] = a0;                              // 16B
        dst[1] = a1;                              // 16B
    }
    if (t == 0) wsf[2 * K] = 0.f;                 // loss
}

// 512 threads = 8 waves; 128 tokens/block (16/wave); 1024 blocks.
// Barriers every 8 K-groups keep all 8 waves in one 16KB pk window (L1).
__launch_bounds__(512)
__global__ void vq_main(const float* __restrict__ z,
                        const float* __restrict__ cb,
                        const unsigned short* __restrict__ pk,
                        float* __restrict__ wsf, int* __restrict__ wsi,
                        float* __restrict__ out,
                        int NT, int K) {
    __shared__ int hist[1024];

    const int tid  = threadIdx.x;
    const int lane = tid & 63;
    const int col  = lane & 15;
    const int quad = lane >> 4;
    const int wtok0 = blockIdx.x * 128 + (tid >> 6) * 16;
    const float* cnormp = wsf + K;
    float* lossp = wsf + 2 * K;
    const bool smallK = (K <= 1024);

    for (int i = tid; i < 1024; i += 512) hist[i] = 0;

    bf16x8 bf0, bf1;
    {
        int tok = wtok0 + col;
        if (tok >= NT) tok = NT - 1;
        const float* zp = z + (size_t)tok * 64 + quad * 8;
        bf0 = cvt8(*(const float4v*)(zp),      *(const float4v*)(zp + 4));
        bf1 = cvt8(*(const float4v*)(zp + 32), *(const float4v*)(zp + 36));
    }

    unsigned k1 = 0u, k2 = 0u;
    const unsigned kmask = 0xFFFFFF00u;
    const int ngrp = (K + 15) >> 4;               // 16-code groups (<=64)
    const unsigned short* pl = pk + lane * 16;    // this lane's fragment column

    for (int tt = 0; tt < ngrp; ++tt) {
        const bf16x8* frag = (const bf16x8*)(pl + (size_t)tt * 1024);
        bf16x8 a0 = frag[0];
        bf16x8 a1 = frag[1];
        float4v cni = *(const float4v*)(cnormp + tt * 16 + quad * 4);

        float4v acc = cni;                        // = BIAS - |c|^2/2
        acc = __builtin_amdgcn_mfma_f32_16x16x32_bf16(a0, bf0, acc, 0, 0, 0);
        acc = __builtin_amdgcn_mfma_f32_16x16x32_bf16(a1, bf1, acc, 0, 0, 0);
        const int iterbase = tt << 2;
        #pragma unroll
        for (int r = 0; r < 4; ++r) {
            unsigned kb = (__float_as_uint(acc[r]) & kmask) | (unsigned)(iterbase + r);
            unsigned lo = k2 > kb ? k2 : kb;
            k2 = k1 < lo ? k1 : lo;
            k1 = k1 > kb ? k1 : kb;
        }
        if ((tt & 7) == 7) __syncthreads();       // window sync: share L1
    }

    // Cooperative exact refine (slim): 4 quad-lanes per token jointly rerank
    // the token's 8 candidates in fp64; incremental best (no ps[] array).
    int ibst;
    {
        int tok = wtok0 + col;
        if (tok >= NT) tok = NT - 1;
        int ia = dec_idx(k1, quad);
        int ib = dec_idx(k2, quad);
        int cand[8];
        #pragma unroll
        for (int q = 0; q < 4; ++q) {
            cand[2 * q]     = __shfl(ia, q * 16 + col, 64);
            cand[2 * q + 1] = __shfl(ib, q * 16 + col, 64);
        }
        const float* zr = z + (size_t)tok * 64 + quad * 16;
        float4v zv0 = *(const float4v*)(zr);
        float4v zv1 = *(const float4v*)(zr + 4);
        float4v zv2 = *(const float4v*)(zr + 8);
        float4v zv3 = *(const float4v*)(zr + 12);
        double bs = 1.0e301; int bi = 0x7fffffff;
        #pragma unroll
        for (int s = 0; s < 8; ++s) {
            int cc = (cand[s] < K) ? cand[s] : 0;
            const float* cr = cb + (size_t)cc * 64 + quad * 16;
            float4v c0 = *(const float4v*)(cr);
            float4v c1 = *(const float4v*)(cr + 4);
            float4v c2 = *(const float4v*)(cr + 8);
            float4v c3 = *(const float4v*)(cr + 12);
            double a = 0.0;
            #pragma unroll
            for (int j = 0; j < 4; ++j) {
                double e0 = (double)zv0[j] - (double)c0[j];
                double e1 = (double)zv1[j] - (double)c1[j];
                double e2 = (double)zv2[j] - (double)c2[j];
                double e3 = (double)zv3[j] - (double)c3[j];
                a = fma(e0, e0, a); a = fma(e1, e1, a);
                a = fma(e2, e2, a); a = fma(e3, e3, a);
            }
            a += __shfl_xor(a, 16, 64);
            a += __shfl_xor(a, 32, 64);
            if (cand[s] < K &&
                (a < bs || (a == bs && cand[s] < bi))) { bs = a; bi = cand[s]; }
        }
        ibst = bi;
    }

    const size_t off_idx = (size_t)NT * 64;
    __syncthreads();                              // hist zero-init visible

    if (lane < 16) {
        int tk = wtok0 + lane;
        if (tk < NT) {
            out[off_idx + tk] = (float)ibst;      // lane==col here: own token
            if (smallK) atomicAdd(&hist[ibst], 1);
            else        atomicAdd(&wsi[ibst], 1);
        }
    }

    // Epilogue: quantized write + commitment loss.
    float lsum = 0.f;
    #pragma unroll
    for (int i = 0; i < 4; ++i) {
        int tw  = i * 4 + quad;                   // 0..15
        int idx = __shfl(ibst, tw, 64);
        int token = wtok0 + tw;
        if (token < NT) {
            int d4 = col * 4;
            float4v zf = *(const float4v*)(z  + (size_t)token * 64 + d4);
            float4v qf = *(const float4v*)(cb + (size_t)idx   * 64 + d4);
            *(float4v*)(out + (size_t)token * 64 + d4) = qf;
            float e0 = zf[0] - qf[0], e1 = zf[1] - qf[1];
            float e2 = zf[2] - qf[2], e3 = zf[3] - qf[3];
            lsum += e0 * e0 + e1 * e1 + e2 * e2 + e3 * e3;
        }
    }
    #pragma unroll
    for (int off = 1; off < 64; off <<= 1) lsum += __shfl_xor(lsum, off, 64);
    if (lane == 0) atomicAdd(lossp, lsum);

    __syncthreads();
    if (smallK) {
        for (int k = tid; k < K; k += 512) {
            int c = hist[k];
            if (c) atomicAdd(&wsi[k], c);
        }
    }
}

// Dimension-partitioned dw scatter (R12, unchanged). Block (chunk, g) owns
// dims [g*16,g*16+16) of ALL K codes; LDS acc[K][16] (64KB). Fully dense —
// no ballot/shfl chains. Exclusive writeout. Block 0 folds the nsum duty.
__launch_bounds__(512)
__global__ void vq_dwred(const float* __restrict__ z,
                         const float* __restrict__ out_idx,
                         const float* __restrict__ cs,
                         float* __restrict__ wsf, const int* __restrict__ wsi,
                         float* __restrict__ partial,
                         float* __restrict__ out,
                         int NT, int K, int nchunks) {
    extern __shared__ float acc[];               // K*16 floats
    __shared__ float red[8];

    const int tid   = threadIdx.x;
    const int lane  = tid & 63;
    const int wave  = tid >> 6;                  // 8 waves
    const int chunk = blockIdx.x >> 2;
    const int g     = blockIdx.x & 3;
    const int tsub  = lane >> 4;
    const int d     = lane & 15;
    const size_t KD = (size_t)K * 64;

    for (int i = tid; i < K * 16; i += 512) acc[i] = 0.f;

    if (blockIdx.x == 0) {
        // folded nsum duty (cnt ready: vq_main completed before this kernel)
        float part = 0.f;
        for (int k = tid; k < K; k += 512)
            part += DECAY * cs[k] + OMD * (float)wsi[k];
        #pragma unroll
        for (int off = 1; off < 64; off <<= 1) part += __shfl_xor(part, off, 64);
        if (lane == 0) red[wave] = part;
        __syncthreads();
        if (tid == 0) {
            float nn = 0.f;
            #pragma unroll
            for (int i = 0; i < 8; ++i) nn += red[i];
            wsf[2 * K + 1] = nn;                                  // n
            out[(size_t)NT * 64 + NT] = wsf[2 * K] / ((float)NT * 64.0f);
        }
    }
    __syncthreads();

    const int C  = (NT + nchunks - 1) / nchunks;
    const int T0 = chunk * C;
    const int T1 = (T0 + C < NT) ? (T0 + C) : NT;
    const float* zs = z + g * 16 + d;

    #pragma unroll 4
    for (int t = T0 + wave * 4 + tsub; t < T1; t += 32) {
        float v   = zs[(size_t)t * 64];
        int  code = (int)out_idx[t];
        atomicAdd(&acc[code * 16 + d], v);
    }
    __syncthreads();

    // exclusive writeout: dims [g*16, g*16+16) of partial[chunk]
    float* pb = partial + (size_t)chunk * KD + g * 16;
    for (int i = tid; i < K * 16; i += 512) {
        int k = i >> 4, dd = i & 15;
        pb[(size_t)k * 64 + dd] = acc[i];
    }
}

// Final: sum chunk partials -> new_ema_w, new_codebook, new_cluster_size.
// 8 independent accumulators -> 8 outstanding loads (latency-bound sum).
__global__ void vq_final(const float* __restrict__ cs,
                         const float* __restrict__ ema,
                         const float* __restrict__ wsf,
                         const int* __restrict__ wsi,
                         const float* __restrict__ partial,
                         float* __restrict__ out, int NT, int K, int S) {
    const int KD = K * 64;
    int t = blockIdx.x * 256 + threadIdx.x;
    if (t >= KD) return;
    const int k = t >> 6;
    const float n = wsf[2 * K + 1];
    float d0 = 0.f, d1 = 0.f, d2 = 0.f, d3 = 0.f;
    float d4 = 0.f, d5 = 0.f, d6 = 0.f, d7 = 0.f;
    int s = 0;
    for (; s + 8 <= S; s += 8) {
        d0 += partial[(size_t)(s + 0) * KD + t];
        d1 += partial[(size_t)(s + 1) * KD + t];
        d2 += partial[(size_t)(s + 2) * KD + t];
        d3 += partial[(size_t)(s + 3) * KD + t];
        d4 += partial[(size_t)(s + 4) * KD + t];
        d5 += partial[(size_t)(s + 5) * KD + t];
        d6 += partial[(size_t)(s + 6) * KD + t];
        d7 += partial[(size_t)(s + 7) * KD + t];
    }
    for (; s < S; ++s) d0 += partial[(size_t)s * KD + t];
    const float dsum = ((d0 + d1) + (d2 + d3)) + ((d4 + d5) + (d6 + d7));
    const float dw = DECAY * ema[t] + OMD * dsum;
    const float ncs = DECAY * cs[k] + OMD * (float)wsi[k];
    const float csn = (ncs + EPSV) / (n + (float)K * EPSV) * n;
    const size_t off_cb  = (size_t)NT * 64 + NT + 1;
    const size_t off_cs  = off_cb + (size_t)KD;
    const size_t off_ema = off_cs + K;
    out[off_cb  + t] = dw / csn;
    out[off_ema + t] = dw;
    if ((t & 63) == 0) out[off_cs + k] = ncs;
}

extern "C" void kernel_launch(void* const* d_in, const int* in_sizes, int n_in,
                              void* d_out, int out_size, void* d_ws, size_t ws_size,
                              hipStream_t stream) {
    const float* z   = (const float*)d_in[0];
    const float* cb  = (const float*)d_in[1];
    const float* cs  = (const float*)d_in[2];
    const float* ema = (const float*)d_in[3];
    float* out = (float*)d_out;
    float* wsf = (float*)d_ws;
    int*   wsi = (int*)d_ws;

    const int NT = in_sizes[0] / 64;
    const int K  = in_sizes[2];
    const int KD = K * 64;

    // ws layout (dwords): [0,K) cnt | [K,2K) cnormp | 2K loss | 2K+1 n |
    //   off_pk: pk (K*32 dwords, 16B-aligned) | off_pa: partials
    const size_t off_pk = (((size_t)2 * K + 2) + 7) & ~(size_t)7;
    const size_t off_pa = off_pk + (size_t)K * 32;

    size_t avail = ws_size / 4;                  // dwords
    int nchunks = 128;
    while (nchunks > 1 && off_pa + (size_t)nchunks * KD > avail)
        nchunks >>= 1;

    unsigned short* pk = (unsigned short*)(wsf + off_pk);
    float* partial = wsf + off_pa;
    const size_t dwlds = (size_t)K * 16 * sizeof(float);   // 64KB @ K=1024

    vq_prep<<<(K * 4 + 255) / 256, 256, 0, stream>>>(cb, wsf, wsi, pk, K, NT);
    vq_main<<<(NT + 127) / 128, 512, 0, stream>>>(z, cb, pk, wsf, wsi, out, NT, K);
    vq_dwred<<<nchunks * 4, 512, dwlds, stream>>>(
        z, out + (size_t)NT * 64, cs, wsf, wsi, partial, out, NT, K, nchunks);
    vq_final<<<(KD + 255) / 256, 256, 0, stream>>>(cs, ema, wsf, wsi, partial,
                                                   out, NT, K, nchunks);
}

// Round 9
// 253.244 us; speedup vs baseline: 1.3715x; 1.3395x over previous
//
#include <hip/hip_runtime.h>
#include <hip/hip_bf16.h>

// VectorQuantizer on MI355X — R16:
//  (a) vq_main: R13 geometry (512 blocks x 8 waves x 32 tok/wave, barrier-free
//      K-loop) + explicit 8-group load/compute batching. R13-R15 triangulated
//      the K-loop as ILP-starved: ~1000cy per iteration = one full L2/L3
//      round-trip serialized per 32B load (VALUBusy 14-24%, FETCH/locality
//      changes didn't move duration). Batch = issue 16 dwordx4 pk loads
//      (8 groups) back-to-back, then 16 MFMA + key updates; 16 outstanding
//      loads/wave x ~3 waves/SIMD covers the latency. cnorm staged to LDS
//      once (removes the third global load stream from the loop).
//      NO launch_bounds min-wave hint (R14: (512,8) -> VGPR32 -> 160MB spill).
//  (b) dw: dimension-partitioned dense scatter (R12, unchanged).
//  (c) vq_final: 8-accumulator interleaved dsum (R15, unchanged).
// Inputs (fp32): z[NT,64], codebook[K,64], cluster_size[K], ema_w[K,64]
// d_out (fp32): quantized[NT*64] | indices[NT] | loss[1] | new_codebook[K*64] |
//   new_cluster_size[K] | new_ema_w[K*64]
// ws dwords: cnt[K](int) | cnormp[K] | loss | n | pad | pk[K*32] |
//   partial[nchunks][K*64]

#define DECAY 0.99f
#define OMD   0.01f
#define EPSV  1e-5f
#define BIASF 192.0f    // folded into MFMA acc init: score' = 192 + z.c - |c|^2/2 > 0

typedef __attribute__((ext_vector_type(8))) __bf16 bf16x8;
typedef __attribute__((ext_vector_type(4))) float  float4v;

static __device__ __forceinline__ bf16x8 cvt8(float4v a, float4v b) {
    bf16x8 r;
    r[0] = (__bf16)a[0]; r[1] = (__bf16)a[1]; r[2] = (__bf16)a[2]; r[3] = (__bf16)a[3];
    r[4] = (__bf16)b[0]; r[5] = (__bf16)b[1]; r[6] = (__bf16)b[2]; r[7] = (__bf16)b[3];
    return r;
}

// key low 8 bits = per-lane candidate number iter = (tt<<2)|r  (K<=1024)
static __device__ __forceinline__ int dec_idx(unsigned key, int quad) {
    int iter = key & 255;
    return ((iter >> 6) << 8) + (((iter >> 2) & 15) << 4) + (quad << 2) + (iter & 3);
}

// Grid covers K*4 threads (one per (t-group, lane) fragment pair) + K cnorm.
__global__ void vq_prep(const float* __restrict__ cb,
                        float* __restrict__ wsf, int* __restrict__ wsi,
                        unsigned short* __restrict__ pk,
                        int K, int NT) {
    int t = blockIdx.x * 256 + threadIdx.x;
    if (t < K) {
        wsi[t] = 0;                               // cnt
        const float4v* cp = (const float4v*)(cb + (size_t)t * 64);
        float s = 0.f;
        #pragma unroll
        for (int i = 0; i < 16; ++i) {
            float4v v = cp[i];
            s += v[0] * v[0] + v[1] * v[1] + v[2] * v[2] + v[3] * v[3];
        }
        wsf[K + t] = BIASF - 0.5f * s;            // cnormp
    }
    if (t < K * 4) {                              // fragment packing
        int tg  = t >> 6;                         // t-group (16 codes)
        int l   = t & 63;                         // lane
        int col = l & 15, q = l >> 4;
        int code = tg * 16 + col;
        bf16x8 a0, a1;
        if (code < K) {
            const float* s0 = cb + (size_t)code * 64 + q * 8;
            a0 = cvt8(*(const float4v*)(s0),      *(const float4v*)(s0 + 4));
            a1 = cvt8(*(const float4v*)(s0 + 32), *(const float4v*)(s0 + 36));
        } else {
            #pragma unroll
            for (int j = 0; j < 8; ++j) { a0[j] = (__bf16)0.f; a1[j] = (__bf16)0.f; }
        }
        bf16x8* dst = (bf16x8*)(pk + (size_t)t * 16);
        dst[0] = a0;                              // 16B
        dst[1] = a1;                              // 16B
    }
    if (t == 0) wsf[2 * K] = 0.f;                 // loss
}

// 512 threads = 8 waves; 256 tokens/block (32/wave); barrier-free K-loop
// with 8-group batched loads.
__launch_bounds__(512)
__global__ void vq_main(const float* __restrict__ z,
                        const float* __restrict__ cb,
                        const unsigned short* __restrict__ pk,
                        float* __restrict__ wsf, int* __restrict__ wsi,
                        float* __restrict__ out,
                        int NT, int K) {
    __shared__ int hist[1024];
    __shared__ float cns[1024];

    const int tid  = threadIdx.x;
    const int lane = tid & 63;
    const int col  = lane & 15;
    const int quad = lane >> 4;
    const int wtok0 = blockIdx.x * 256 + (tid >> 6) * 32;
    const float* cnormp = wsf + K;
    float* lossp = wsf + 2 * K;
    const bool smallK = (K <= 1024);

    for (int i = tid; i < 1024; i += 512) {
        hist[i] = 0;
        cns[i] = (i < K) ? cnormp[i] : 0.f;
    }

    bf16x8 bf0[2], bf1[2];
    #pragma unroll
    for (int g = 0; g < 2; ++g) {
        int tok = wtok0 + g * 16 + col;
        if (tok >= NT) tok = NT - 1;
        const float* zp = z + (size_t)tok * 64 + quad * 8;
        bf0[g] = cvt8(*(const float4v*)(zp),      *(const float4v*)(zp + 4));
        bf1[g] = cvt8(*(const float4v*)(zp + 32), *(const float4v*)(zp + 36));
    }
    __syncthreads();                              // cns + hist ready

    unsigned k1[2] = { 0u, 0u }, k2[2] = { 0u, 0u };
    const unsigned kmask = 0xFFFFFF00u;
    const int ngrp = (K + 15) >> 4;               // 16-code groups (<=64)
    const unsigned short* pl = pk + lane * 16;    // this lane's fragment column

    for (int b = 0; b < ngrp; b += 8) {
        // ---- load phase: 16 global dwordx4 + 8 LDS float4, all independent
        bf16x8 A0[8], A1[8];
        float4v CN[8];
        #pragma unroll
        for (int i = 0; i < 8; ++i) {
            int tt = b + i; if (tt >= ngrp) tt = ngrp - 1;
            const bf16x8* f = (const bf16x8*)(pl + (size_t)tt * 1024);
            A0[i] = f[0];
            A1[i] = f[1];
            CN[i] = *(const float4v*)(cns + tt * 16 + quad * 4);
        }
        // ---- compute phase: 16 MFMA + key updates
        #pragma unroll
        for (int i = 0; i < 8; ++i) {
            int tt = b + i;
            if (tt < ngrp) {
                const int iterbase = tt << 2;
                #pragma unroll
                for (int g = 0; g < 2; ++g) {
                    float4v acc = CN[i];          // = BIAS - |c|^2/2
                    acc = __builtin_amdgcn_mfma_f32_16x16x32_bf16(A0[i], bf0[g], acc, 0, 0, 0);
                    acc = __builtin_amdgcn_mfma_f32_16x16x32_bf16(A1[i], bf1[g], acc, 0, 0, 0);
                    #pragma unroll
                    for (int r = 0; r < 4; ++r) {
                        unsigned kb = (__float_as_uint(acc[r]) & kmask) | (unsigned)(iterbase + r);
                        unsigned lo = k2[g] > kb ? k2[g] : kb;
                        k2[g] = k1[g] < lo ? k1[g] : lo;
                        k1[g] = k1[g] > kb ? k1[g] : kb;
                    }
                }
            }
        }
    }

    // Cooperative exact refine (R9/R13): 4 quad-lanes per token jointly rerank
    // the token's 8 candidates in fp64; each lane covers a 16-dim slice.
    int ibst[2];
    #pragma unroll
    for (int g = 0; g < 2; ++g) {
        int tok = wtok0 + g * 16 + col;
        if (tok >= NT) tok = NT - 1;
        int ia = dec_idx(k1[g], quad);
        int ib = dec_idx(k2[g], quad);
        int cand[8];
        #pragma unroll
        for (int q = 0; q < 4; ++q) {
            cand[2 * q]     = __shfl(ia, q * 16 + col, 64);
            cand[2 * q + 1] = __shfl(ib, q * 16 + col, 64);
        }
        const float* zr = z + (size_t)tok * 64 + quad * 16;
        float4v zv0 = *(const float4v*)(zr);
        float4v zv1 = *(const float4v*)(zr + 4);
        float4v zv2 = *(const float4v*)(zr + 8);
        float4v zv3 = *(const float4v*)(zr + 12);
        double ps[8];
        #pragma unroll
        for (int s = 0; s < 8; ++s) {
            int cc = (cand[s] < K) ? cand[s] : 0;
            const float* cr = cb + (size_t)cc * 64 + quad * 16;
            float4v c0 = *(const float4v*)(cr);
            float4v c1 = *(const float4v*)(cr + 4);
            float4v c2 = *(const float4v*)(cr + 8);
            float4v c3 = *(const float4v*)(cr + 12);
            double a = 0.0;
            #pragma unroll
            for (int j = 0; j < 4; ++j) {
                double e0 = (double)zv0[j] - (double)c0[j];
                double e1 = (double)zv1[j] - (double)c1[j];
                double e2 = (double)zv2[j] - (double)c2[j];
                double e3 = (double)zv3[j] - (double)c3[j];
                a = fma(e0, e0, a); a = fma(e1, e1, a);
                a = fma(e2, e2, a); a = fma(e3, e3, a);
            }
            ps[s] = (cand[s] < K) ? a : 1.0e300;
        }
        #pragma unroll
        for (int s = 0; s < 8; ++s) {
            ps[s] += __shfl_xor(ps[s], 16, 64);
            ps[s] += __shfl_xor(ps[s], 32, 64);
        }
        double bs = ps[0]; int bi = cand[0];
        #pragma unroll
        for (int s = 1; s < 8; ++s) {
            if (ps[s] < bs || (ps[s] == bs && cand[s] < bi)) { bs = ps[s]; bi = cand[s]; }
        }
        ibst[g] = bi;
    }

    const size_t off_idx = (size_t)NT * 64;

    if (lane < 32) {
        int tk = wtok0 + lane;
        if (tk < NT) {
            int ib = (lane < 16) ? ibst[0] : ibst[1];
            out[off_idx + tk] = (float)ib;
            if (smallK) atomicAdd(&hist[ib], 1);
            else        atomicAdd(&wsi[ib], 1);
        }
    }

    // Epilogue: quantized write + commitment loss.
    float lsum = 0.f;
    #pragma unroll
    for (int i = 0; i < 8; ++i) {
        int tw  = i * 4 + quad;
        int g   = i >> 2;
        int idx = __shfl(ibst[g], tw & 15, 64);
        int token = wtok0 + tw;
        if (token < NT) {
            int d4 = col * 4;
            float4v zf = *(const float4v*)(z  + (size_t)token * 64 + d4);
            float4v qf = *(const float4v*)(cb + (size_t)idx   * 64 + d4);
            *(float4v*)(out + (size_t)token * 64 + d4) = qf;
            float e0 = zf[0] - qf[0], e1 = zf[1] - qf[1];
            float e2 = zf[2] - qf[2], e3 = zf[3] - qf[3];
            lsum += e0 * e0 + e1 * e1 + e2 * e2 + e3 * e3;
        }
    }
    #pragma unroll
    for (int off = 1; off < 64; off <<= 1) lsum += __shfl_xor(lsum, off, 64);
    if (lane == 0) atomicAdd(lossp, lsum);

    __syncthreads();
    if (smallK) {
        for (int k = tid; k < K; k += 512) {
            int c = hist[k];
            if (c) atomicAdd(&wsi[k], c);
        }
    }
}

// Dimension-partitioned dw scatter (R12, unchanged). Block (chunk, g) owns
// dims [g*16,g*16+16) of ALL K codes; LDS acc[K][16] (64KB). Fully dense —
// no ballot/shfl chains. Exclusive writeout. Block 0 folds the nsum duty.
__launch_bounds__(512)
__global__ void vq_dwred(const float* __restrict__ z,
                         const float* __restrict__ out_idx,
                         const float* __restrict__ cs,
                         float* __restrict__ wsf, const int* __restrict__ wsi,
                         float* __restrict__ partial,
                         float* __restrict__ out,
                         int NT, int K, int nchunks) {
    extern __shared__ float acc[];               // K*16 floats
    __shared__ float red[8];

    const int tid   = threadIdx.x;
    const int lane  = tid & 63;
    const int wave  = tid >> 6;                  // 8 waves
    const int chunk = blockIdx.x >> 2;
    const int g     = blockIdx.x & 3;
    const int tsub  = lane >> 4;
    const int d     = lane & 15;
    const size_t KD = (size_t)K * 64;

    for (int i = tid; i < K * 16; i += 512) acc[i] = 0.f;

    if (blockIdx.x == 0) {
        // folded nsum duty (cnt ready: vq_main completed before this kernel)
        float part = 0.f;
        for (int k = tid; k < K; k += 512)
            part += DECAY * cs[k] + OMD * (float)wsi[k];
        #pragma unroll
        for (int off = 1; off < 64; off <<= 1) part += __shfl_xor(part, off, 64);
        if (lane == 0) red[wave] = part;
        __syncthreads();
        if (tid == 0) {
            float nn = 0.f;
            #pragma unroll
            for (int i = 0; i < 8; ++i) nn += red[i];
            wsf[2 * K + 1] = nn;                                  // n
            out[(size_t)NT * 64 + NT] = wsf[2 * K] / ((float)NT * 64.0f);
        }
    }
    __syncthreads();

    const int C  = (NT + nchunks - 1) / nchunks;
    const int T0 = chunk * C;
    const int T1 = (T0 + C < NT) ? (T0 + C) : NT;
    const float* zs = z + g * 16 + d;

    #pragma unroll 4
    for (int t = T0 + wave * 4 + tsub; t < T1; t += 32) {
        float v   = zs[(size_t)t * 64];
        int  code = (int)out_idx[t];
        atomicAdd(&acc[code * 16 + d], v);
    }
    __syncthreads();

    // exclusive writeout: dims [g*16, g*16+16) of partial[chunk]
    float* pb = partial + (size_t)chunk * KD + g * 16;
    for (int i = tid; i < K * 16; i += 512) {
        int k = i >> 4, dd = i & 15;
        pb[(size_t)k * 64 + dd] = acc[i];
    }
}

// Final: sum chunk partials -> new_ema_w, new_codebook, new_cluster_size.
// 8 independent accumulators -> 8 outstanding loads (latency-bound sum).
__global__ void vq_final(const float* __restrict__ cs,
                         const float* __restrict__ ema,
                         const float* __restrict__ wsf,
                         const int* __restrict__ wsi,
                         const float* __restrict__ partial,
                         float* __restrict__ out, int NT, int K, int S) {
    const int KD = K * 64;
    int t = blockIdx.x * 256 + threadIdx.x;
    if (t >= KD) return;
    const int k = t >> 6;
    const float n = wsf[2 * K + 1];
    float d0 = 0.f, d1 = 0.f, d2 = 0.f, d3 = 0.f;
    float d4 = 0.f, d5 = 0.f, d6 = 0.f, d7 = 0.f;
    int s = 0;
    for (; s + 8 <= S; s += 8) {
        d0 += partial[(size_t)(s + 0) * KD + t];
        d1 += partial[(size_t)(s + 1) * KD + t];
        d2 += partial[(size_t)(s + 2) * KD + t];
        d3 += partial[(size_t)(s + 3) * KD + t];
        d4 += partial[(size_t)(s + 4) * KD + t];
        d5 += partial[(size_t)(s + 5) * KD + t];
        d6 += partial[(size_t)(s + 6) * KD + t];
        d7 += partial[(size_t)(s + 7) * KD + t];
    }
    for (; s < S; ++s) d0 += partial[(size_t)s * KD + t];
    const float dsum = ((d0 + d1) + (d2 + d3)) + ((d4 + d5) + (d6 + d7));
    const float dw = DECAY * ema[t] + OMD * dsum;
    const float ncs = DECAY * cs[k] + OMD * (float)wsi[k];
    const float csn = (ncs + EPSV) / (n + (float)K * EPSV) * n;
    const size_t off_cb  = (size_t)NT * 64 + NT + 1;
    const size_t off_cs  = off_cb + (size_t)KD;
    const size_t off_ema = off_cs + K;
    out[off_cb  + t] = dw / csn;
    out[off_ema + t] = dw;
    if ((t & 63) == 0) out[off_cs + k] = ncs;
}

extern "C" void kernel_launch(void* const* d_in, const int* in_sizes, int n_in,
                              void* d_out, int out_size, void* d_ws, size_t ws_size,
                              hipStream_t stream) {
    const float* z   = (const float*)d_in[0];
    const float* cb  = (const float*)d_in[1];
    const float* cs  = (const float*)d_in[2];
    const float* ema = (const float*)d_in[3];
    float* out = (float*)d_out;
    float* wsf = (float*)d_ws;
    int*   wsi = (int*)d_ws;

    const int NT = in_sizes[0] / 64;
    const int K  = in_sizes[2];
    const int KD = K * 64;

    // ws layout (dwords): [0,K) cnt | [K,2K) cnormp | 2K loss | 2K+1 n |
    //   off_pk: pk (K*32 dwords, 16B-aligned) | off_pa: partials
    const size_t off_pk = (((size_t)2 * K + 2) + 7) & ~(size_t)7;
    const size_t off_pa = off_pk + (size_t)K * 32;

    size_t avail = ws_size / 4;                  // dwords
    int nchunks = 128;
    while (nchunks > 1 && off_pa + (size_t)nchunks * KD > avail)
        nchunks >>= 1;

    unsigned short* pk = (unsigned short*)(wsf + off_pk);
    float* partial = wsf + off_pa;
    const size_t dwlds = (size_t)K * 16 * sizeof(float);   // 64KB @ K=1024

    vq_prep<<<(K * 4 + 255) / 256, 256, 0, stream>>>(cb, wsf, wsi, pk, K, NT);
    vq_main<<<(NT + 255) / 256, 512, 0, stream>>>(z, cb, pk, wsf, wsi, out, NT, K);
    vq_dwred<<<nchunks * 4, 512, dwlds, stream>>>(
        z, out + (size_t)NT * 64, cs, wsf, wsi, partial, out, NT, K, nchunks);
    vq_final<<<(KD + 255) / 256, 256, 0, stream>>>(cs, ema, wsf, wsi, partial,
                                                   out, NT, K, nchunks);
}

// Round 10
// 242.171 us; speedup vs baseline: 1.4342x; 1.0457x over previous
//
#include <hip/hip_runtime.h>
#include <hip/hip_bf16.h>

// VectorQuantizer on MI355X — R17:
//  (a) vq_main SPLIT into vq_assign (R12's proven K-loop + coop fp64 refine ->
//      indices/counts only) and vq_quant (1 float4/thread coalesced gather:
//      quantized write + commitment loss). Purpose: per-phase rocprof timing —
//      R13/R14/R15/R16 all landed 108-120us across four different codebook
//      delivery schemes (LDS-staged / pk-stream / windowed / batched) with
//      VALUBusy 14-28%; models say 15-40us. The aggregate counters can't name
//      the consumer; the dispatch split measures it. Also a likely win: the
//      epilogue's memory work gets clean coalesced parallelism.
//  (b) dw: dimension-partitioned dense scatter (R12, unchanged).
//  (c) vq_prep: pk packing dropped (dead with the R12-style assign).
// Inputs (fp32): z[NT,64], codebook[K,64], cluster_size[K], ema_w[K,64]
// d_out (fp32): quantized[NT*64] | indices[NT] | loss[1] | new_codebook[K*64] |
//   new_cluster_size[K] | new_ema_w[K*64]
// ws dwords: cnt[K](int) | cnormp[K] | loss | n | partial[nchunks][K*64]

#define DECAY 0.99f
#define OMD   0.01f
#define EPSV  1e-5f
#define BIASF 192.0f    // folded into MFMA acc init: score' = 192 + z.c - |c|^2/2 > 0

typedef __attribute__((ext_vector_type(8))) __bf16 bf16x8;
typedef __attribute__((ext_vector_type(4))) float  float4v;

static __device__ __forceinline__ unsigned short bfbits(float f) {
    __bf16 h = (__bf16)f;
    return __builtin_bit_cast(unsigned short, h);
}
static __device__ __forceinline__ bf16x8 cvt8(float4v a, float4v b) {
    bf16x8 r;
    r[0] = (__bf16)a[0]; r[1] = (__bf16)a[1]; r[2] = (__bf16)a[2]; r[3] = (__bf16)a[3];
    r[4] = (__bf16)b[0]; r[5] = (__bf16)b[1]; r[6] = (__bf16)b[2]; r[7] = (__bf16)b[3];
    return r;
}

// key low 8 bits = per-lane candidate number iter = (c<<6)|(t<<2)|r
static __device__ __forceinline__ int dec_idx(unsigned key, int quad) {
    int iter = key & 255;
    return ((iter >> 6) << 8) + (((iter >> 2) & 15) << 4) + (quad << 2) + (iter & 3);
}

__global__ void vq_prep(const float* __restrict__ cb,
                        float* __restrict__ wsf, int* __restrict__ wsi,
                        int K, int NT) {
    int t = blockIdx.x * 256 + threadIdx.x;
    if (t < K) {
        wsi[t] = 0;                               // cnt
        const float4v* cp = (const float4v*)(cb + (size_t)t * 64);
        float s = 0.f;
        #pragma unroll
        for (int i = 0; i < 16; ++i) {
            float4v v = cp[i];
            s += v[0] * v[0] + v[1] * v[1] + v[2] * v[2] + v[3] * v[3];
        }
        wsf[K + t] = BIASF - 0.5f * s;            // cnormp
    }
    if (t == 0) wsf[2 * K] = 0.f;                 // loss
}

// 512 threads = 8 waves; 256 tokens/block (32/wave); codebook bf16 in LDS.
// R12's vq_main minus the quantized/loss epilogue: writes indices + counts.
__launch_bounds__(512)
__global__ void vq_assign(const float* __restrict__ z,
                          const float* __restrict__ cb,
                          float* __restrict__ wsf, int* __restrict__ wsi,
                          float* __restrict__ out,
                          int NT, int K) {
    __shared__ __align__(16) unsigned short cbs[256 * 72];   // 36 KB
    __shared__ float cns[256];
    __shared__ int hist[1024];

    const int tid  = threadIdx.x;
    const int lane = tid & 63;
    const int wave = tid >> 6;
    const int col  = lane & 15;
    const int quad = lane >> 4;
    const int wtok0 = blockIdx.x * 256 + wave * 32;
    const float* cnormp = wsf + K;
    const bool smallK = (K <= 1024);

    for (int i = tid; i < 1024; i += 512) hist[i] = 0;

    bf16x8 bf0[2], bf1[2];
    #pragma unroll
    for (int g = 0; g < 2; ++g) {
        int tok = wtok0 + g * 16 + col;
        if (tok >= NT) tok = NT - 1;
        const float* zp = z + (size_t)tok * 64 + quad * 8;
        float4v f0 = *(const float4v*)(zp);
        float4v f1 = *(const float4v*)(zp + 4);
        float4v f2 = *(const float4v*)(zp + 32);
        float4v f3 = *(const float4v*)(zp + 36);
        bf0[g] = cvt8(f0, f1);
        bf1[g] = cvt8(f2, f3);
    }

    unsigned k1[2] = { 0u, 0u }, k2[2] = { 0u, 0u };
    const unsigned kmask = 0xFFFFFF00u;
    const int nchunk = (K + 255) >> 8;

    for (int c = 0; c < nchunk; ++c) {
        #pragma unroll
        for (int i = 0; i < 8; ++i) {
            int f4 = (i * 512 + tid) * 4;
            int row = f4 >> 6, d = f4 & 63;
            int code = c * 256 + row;
            uint2 p;
            if (code < K) {
                float4v v = *(const float4v*)(cb + (size_t)code * 64 + d);
                p.x = (unsigned int)bfbits(v[0]) | ((unsigned int)bfbits(v[1]) << 16);
                p.y = (unsigned int)bfbits(v[2]) | ((unsigned int)bfbits(v[3]) << 16);
            } else { p.x = 0u; p.y = 0u; }
            *(uint2*)(&cbs[row * 72 + d]) = p;
        }
        if (tid < 256) {
            int code = c * 256 + tid;
            cns[tid] = (code < K) ? cnormp[code] : 0.0f;
        }
        __syncthreads();

        #pragma unroll 4
        for (int t = 0; t < 16; ++t) {
            const unsigned short* arow = cbs + (t * 16 + col) * 72;
            bf16x8 a0 = *(const bf16x8*)(arow + quad * 8);
            bf16x8 a1 = *(const bf16x8*)(arow + 32 + quad * 8);
            float4v cni = *(const float4v*)(cns + t * 16 + quad * 4);
            const int iterbase = (c << 6) | (t << 2);
            #pragma unroll
            for (int g = 0; g < 2; ++g) {
                float4v acc = cni;              // = BIAS - |c|^2/2
                acc = __builtin_amdgcn_mfma_f32_16x16x32_bf16(a0, bf0[g], acc, 0, 0, 0);
                acc = __builtin_amdgcn_mfma_f32_16x16x32_bf16(a1, bf1[g], acc, 0, 0, 0);
                #pragma unroll
                for (int r = 0; r < 4; ++r) {
                    unsigned kb = (__float_as_uint(acc[r]) & kmask) | (unsigned)(iterbase + r);
                    unsigned lo = k2[g] > kb ? k2[g] : kb;
                    k2[g] = k1[g] < lo ? k1[g] : lo;
                    k1[g] = k1[g] > kb ? k1[g] : kb;
                }
            }
        }
        __syncthreads();
    }

    // Cooperative exact refine (R9): 4 quad-lanes per token jointly rerank the
    // token's 8 candidates in fp64; each lane covers a 16-dim slice.
    int ibst[2];
    #pragma unroll
    for (int g = 0; g < 2; ++g) {
        int tok = wtok0 + g * 16 + col;
        if (tok >= NT) tok = NT - 1;
        int ia = dec_idx(k1[g], quad);
        int ib = dec_idx(k2[g], quad);
        int cand[8];
        #pragma unroll
        for (int q = 0; q < 4; ++q) {
            cand[2 * q]     = __shfl(ia, q * 16 + col, 64);
            cand[2 * q + 1] = __shfl(ib, q * 16 + col, 64);
        }
        const float* zr = z + (size_t)tok * 64 + quad * 16;
        float4v zv0 = *(const float4v*)(zr);
        float4v zv1 = *(const float4v*)(zr + 4);
        float4v zv2 = *(const float4v*)(zr + 8);
        float4v zv3 = *(const float4v*)(zr + 12);
        double ps[8];
        #pragma unroll
        for (int s = 0; s < 8; ++s) {
            int cc = (cand[s] < K) ? cand[s] : 0;
            const float* cr = cb + (size_t)cc * 64 + quad * 16;
            float4v c0 = *(const float4v*)(cr);
            float4v c1 = *(const float4v*)(cr + 4);
            float4v c2 = *(const float4v*)(cr + 8);
            float4v c3 = *(const float4v*)(cr + 12);
            double a = 0.0;
            #pragma unroll
            for (int j = 0; j < 4; ++j) {
                double e0 = (double)zv0[j] - (double)c0[j];
                double e1 = (double)zv1[j] - (double)c1[j];
                double e2 = (double)zv2[j] - (double)c2[j];
                double e3 = (double)zv3[j] - (double)c3[j];
                a = fma(e0, e0, a); a = fma(e1, e1, a);
                a = fma(e2, e2, a); a = fma(e3, e3, a);
            }
            ps[s] = (cand[s] < K) ? a : 1.0e300;
        }
        #pragma unroll
        for (int s = 0; s < 8; ++s) {
            ps[s] += __shfl_xor(ps[s], 16, 64);
            ps[s] += __shfl_xor(ps[s], 32, 64);
        }
        double bs = ps[0]; int bi = cand[0];
        #pragma unroll
        for (int s = 1; s < 8; ++s) {
            if (ps[s] < bs || (ps[s] == bs && cand[s] < bi)) { bs = ps[s]; bi = cand[s]; }
        }
        ibst[g] = bi;
    }

    const size_t off_idx = (size_t)NT * 64;

    if (lane < 32) {
        int tk = wtok0 + lane;
        if (tk < NT) {
            int ib = (lane < 16) ? ibst[0] : ibst[1];
            out[off_idx + tk] = (float)ib;
            if (smallK) atomicAdd(&hist[ib], 1);
            else        atomicAdd(&wsi[ib], 1);
        }
    }

    __syncthreads();
    if (smallK) {
        for (int k = tid; k < K; k += 512) {
            int c = hist[k];
            if (c) atomicAdd(&wsi[k], c);
        }
    }
}

// Quantized gather + commitment loss. One float4 per thread, fully coalesced
// z read / out write; cb row broadcast across each token's 16 threads.
__launch_bounds__(1024)
__global__ void vq_quant(const float* __restrict__ z,
                         const float* __restrict__ cb,
                         const float* __restrict__ out_idx,
                         float* __restrict__ out,
                         float* __restrict__ lossp, int NT) {
    __shared__ float red[16];
    const int tid  = threadIdx.x;
    const int lane = tid & 63;
    const int wave = tid >> 6;
    const int gt   = blockIdx.x * 1024 + tid;     // one float4 slot

    float lsum = 0.f;
    if (gt < NT * 16) {
        int token = gt >> 4, seg = gt & 15;
        int idx = (int)out_idx[token];
        const float4v zf = *(const float4v*)(z  + (size_t)token * 64 + seg * 4);
        const float4v qf = *(const float4v*)(cb + (size_t)idx   * 64 + seg * 4);
        *(float4v*)(out + (size_t)token * 64 + seg * 4) = qf;
        float e0 = zf[0] - qf[0], e1 = zf[1] - qf[1];
        float e2 = zf[2] - qf[2], e3 = zf[3] - qf[3];
        lsum = e0 * e0 + e1 * e1 + e2 * e2 + e3 * e3;
    }
    #pragma unroll
    for (int off = 1; off < 64; off <<= 1) lsum += __shfl_xor(lsum, off, 64);
    if (lane == 0) red[wave] = lsum;
    __syncthreads();
    if (tid == 0) {
        float s = 0.f;
        #pragma unroll
        for (int i = 0; i < 16; ++i) s += red[i];
        atomicAdd(lossp, s);
    }
}

// Dimension-partitioned dw scatter (R12, unchanged). Block (chunk, g) owns
// dims [g*16,g*16+16) of ALL K codes; LDS acc[K][16] (64KB). Fully dense —
// no ballot/shfl chains. Exclusive writeout. Block 0 folds the nsum duty.
__launch_bounds__(512)
__global__ void vq_dwred(const float* __restrict__ z,
                         const float* __restrict__ out_idx,
                         const float* __restrict__ cs,
                         float* __restrict__ wsf, const int* __restrict__ wsi,
                         float* __restrict__ partial,
                         float* __restrict__ out,
                         int NT, int K, int nchunks) {
    extern __shared__ float acc[];               // K*16 floats
    __shared__ float red[8];

    const int tid   = threadIdx.x;
    const int lane  = tid & 63;
    const int wave  = tid >> 6;                  // 8 waves
    const int chunk = blockIdx.x >> 2;
    const int g     = blockIdx.x & 3;
    const int tsub  = lane >> 4;
    const int d     = lane & 15;
    const size_t KD = (size_t)K * 64;

    for (int i = tid; i < K * 16; i += 512) acc[i] = 0.f;

    if (blockIdx.x == 0) {
        // folded nsum duty (cnt + loss final: assign/quant completed earlier)
        float part = 0.f;
        for (int k = tid; k < K; k += 512)
            part += DECAY * cs[k] + OMD * (float)wsi[k];
        #pragma unroll
        for (int off = 1; off < 64; off <<= 1) part += __shfl_xor(part, off, 64);
        if (lane == 0) red[wave] = part;
        __syncthreads();
        if (tid == 0) {
            float nn = 0.f;
            #pragma unroll
            for (int i = 0; i < 8; ++i) nn += red[i];
            wsf[2 * K + 1] = nn;                                  // n
            out[(size_t)NT * 64 + NT] = wsf[2 * K] / ((float)NT * 64.0f);
        }
    }
    __syncthreads();

    const int C  = (NT + nchunks - 1) / nchunks;
    const int T0 = chunk * C;
    const int T1 = (T0 + C < NT) ? (T0 + C) : NT;
    const float* zs = z + g * 16 + d;

    #pragma unroll 4
    for (int t = T0 + wave * 4 + tsub; t < T1; t += 32) {
        float v   = zs[(size_t)t * 64];
        int  code = (int)out_idx[t];
        atomicAdd(&acc[code * 16 + d], v);
    }
    __syncthreads();

    // exclusive writeout: dims [g*16, g*16+16) of partial[chunk]
    float* pb = partial + (size_t)chunk * KD + g * 16;
    for (int i = tid; i < K * 16; i += 512) {
        int k = i >> 4, dd = i & 15;
        pb[(size_t)k * 64 + dd] = acc[i];
    }
}

// Final: sum chunk partials -> new_ema_w, new_codebook, new_cluster_size.
// 8 independent accumulators -> 8 outstanding loads (latency-bound sum).
__global__ void vq_final(const float* __restrict__ cs,
                         const float* __restrict__ ema,
                         const float* __restrict__ wsf,
                         const int* __restrict__ wsi,
                         const float* __restrict__ partial,
                         float* __restrict__ out, int NT, int K, int S) {
    const int KD = K * 64;
    int t = blockIdx.x * 256 + threadIdx.x;
    if (t >= KD) return;
    const int k = t >> 6;
    const float n = wsf[2 * K + 1];
    float d0 = 0.f, d1 = 0.f, d2 = 0.f, d3 = 0.f;
    float d4 = 0.f, d5 = 0.f, d6 = 0.f, d7 = 0.f;
    int s = 0;
    for (; s + 8 <= S; s += 8) {
        d0 += partial[(size_t)(s + 0) * KD + t];
        d1 += partial[(size_t)(s + 1) * KD + t];
        d2 += partial[(size_t)(s + 2) * KD + t];
        d3 += partial[(size_t)(s + 3) * KD + t];
        d4 += partial[(size_t)(s + 4) * KD + t];
        d5 += partial[(size_t)(s + 5) * KD + t];
        d6 += partial[(size_t)(s + 6) * KD + t];
        d7 += partial[(size_t)(s + 7) * KD + t];
    }
    for (; s < S; ++s) d0 += partial[(size_t)s * KD + t];
    const float dsum = ((d0 + d1) + (d2 + d3)) + ((d4 + d5) + (d6 + d7));
    const float dw = DECAY * ema[t] + OMD * dsum;
    const float ncs = DECAY * cs[k] + OMD * (float)wsi[k];
    const float csn = (ncs + EPSV) / (n + (float)K * EPSV) * n;
    const size_t off_cb  = (size_t)NT * 64 + NT + 1;
    const size_t off_cs  = off_cb + (size_t)KD;
    const size_t off_ema = off_cs + K;
    out[off_cb  + t] = dw / csn;
    out[off_ema + t] = dw;
    if ((t & 63) == 0) out[off_cs + k] = ncs;
}

extern "C" void kernel_launch(void* const* d_in, const int* in_sizes, int n_in,
                              void* d_out, int out_size, void* d_ws, size_t ws_size,
                              hipStream_t stream) {
    const float* z   = (const float*)d_in[0];
    const float* cb  = (const float*)d_in[1];
    const float* cs  = (const float*)d_in[2];
    const float* ema = (const float*)d_in[3];
    float* out = (float*)d_out;
    float* wsf = (float*)d_ws;
    int*   wsi = (int*)d_ws;

    const int NT = in_sizes[0] / 64;
    const int K  = in_sizes[2];
    const int KD = K * 64;

    // ws layout (dwords): [0,K) cnt | [K,2K) cnormp | 2K loss | 2K+1 n |
    //   partial[nchunks][K*64]
    size_t avail = ws_size / 4;                  // dwords
    int nchunks = 128;
    while (nchunks > 1 && (size_t)2 * K + 2 + (size_t)nchunks * KD > avail)
        nchunks >>= 1;

    float* partial = wsf + 2 * K + 2;
    const size_t dwlds = (size_t)K * 16 * sizeof(float);   // 64KB @ K=1024

    vq_prep<<<(K + 255) / 256, 256, 0, stream>>>(cb, wsf, wsi, K, NT);
    vq_assign<<<(NT + 255) / 256, 512, 0, stream>>>(z, cb, wsf, wsi, out, NT, K);
    vq_quant<<<(NT * 16 + 1023) / 1024, 1024, 0, stream>>>(
        z, cb, out + (size_t)NT * 64, out, wsf + 2 * K, NT);
    vq_dwred<<<nchunks * 4, 512, dwlds, stream>>>(
        z, out + (size_t)NT * 64, cs, wsf, wsi, partial, out, NT, K, nchunks);
    vq_final<<<(KD + 255) / 256, 256, 0, stream>>>(cs, ema, wsf, wsi, partial,
                                                   out, NT, K, nchunks);
}

// Round 11
// 208.985 us; speedup vs baseline: 1.6620x; 1.1588x over previous
//
#include <hip/hip_runtime.h>
#include <hip/hip_bf16.h>

// VectorQuantizer on MI355X — R18:
//  (a) vq_assign: KCHUNK 256->128 (LDS 41984->23KB) -> 4 blocks/CU (wave-cap
//      ceiling, was 3) and halved per-barrier staging drain. R17 split showed
//      assign=77us with ~28us VALU issue (top-2 key updates) + ~45us stall at
//      3-block residency. dec_idx generalized to grp*16+quad*4+r (old form
//      hard-coded 16 groups/chunk).
//  (b) vq_quant FUSED into vq_dwred: each (chunk,g) block already scans its
//      tokens' dims [g*16,+16) — add cb gather, quantized write, loss slice.
//      Saves a 32MB z re-read + a launch. Loss normalize moved to vq_final.
//  (c) nchunks 128->64: partial traffic 64->32MB, 256 dwred blocks.
// Inputs (fp32): z[NT,64], codebook[K,64], cluster_size[K], ema_w[K,64]
// d_out (fp32): quantized[NT*64] | indices[NT] | loss[1] | new_codebook[K*64] |
//   new_cluster_size[K] | new_ema_w[K*64]
// ws dwords: cnt[K](int) | cnormp[K] | loss | n | partial[nchunks][K*64]

#define DECAY 0.99f
#define OMD   0.01f
#define EPSV  1e-5f
#define BIASF 192.0f    // folded into MFMA acc init: score' = 192 + z.c - |c|^2/2 > 0
#define KCH   128       // codes per staged chunk (LDS 128*72*2B = 18KB)

typedef __attribute__((ext_vector_type(8))) __bf16 bf16x8;
typedef __attribute__((ext_vector_type(4))) float  float4v;

static __device__ __forceinline__ unsigned short bfbits(float f) {
    __bf16 h = (__bf16)f;
    return __builtin_bit_cast(unsigned short, h);
}
static __device__ __forceinline__ bf16x8 cvt8(float4v a, float4v b) {
    bf16x8 r;
    r[0] = (__bf16)a[0]; r[1] = (__bf16)a[1]; r[2] = (__bf16)a[2]; r[3] = (__bf16)a[3];
    r[4] = (__bf16)b[0]; r[5] = (__bf16)b[1]; r[6] = (__bf16)b[2]; r[7] = (__bf16)b[3];
    return r;
}

// key low 8 bits: iter = (global_group<<2)|r ; code = grp*16 + quad*4 + r
static __device__ __forceinline__ int dec_idx(unsigned key, int quad) {
    int iter = key & 255;
    return ((iter >> 2) << 4) + (quad << 2) + (iter & 3);
}

__global__ void vq_prep(const float* __restrict__ cb,
                        float* __restrict__ wsf, int* __restrict__ wsi,
                        int K, int NT) {
    int t = blockIdx.x * 256 + threadIdx.x;
    if (t < K) {
        wsi[t] = 0;                               // cnt
        const float4v* cp = (const float4v*)(cb + (size_t)t * 64);
        float s = 0.f;
        #pragma unroll
        for (int i = 0; i < 16; ++i) {
            float4v v = cp[i];
            s += v[0] * v[0] + v[1] * v[1] + v[2] * v[2] + v[3] * v[3];
        }
        wsf[K + t] = BIASF - 0.5f * s;            // cnormp
    }
    if (t == 0) wsf[2 * K] = 0.f;                 // loss
}

// 512 threads = 8 waves; 256 tokens/block (32/wave); codebook bf16 in LDS,
// staged in 128-code chunks (23KB LDS total -> 4 blocks/CU).
__launch_bounds__(512)
__global__ void vq_assign(const float* __restrict__ z,
                          const float* __restrict__ cb,
                          float* __restrict__ wsf, int* __restrict__ wsi,
                          float* __restrict__ out,
                          int NT, int K) {
    __shared__ __align__(16) unsigned short cbs[KCH * 72];   // 18 KB
    __shared__ float cns[KCH];
    __shared__ int hist[1024];

    const int tid  = threadIdx.x;
    const int lane = tid & 63;
    const int wave = tid >> 6;
    const int col  = lane & 15;
    const int quad = lane >> 4;
    const int wtok0 = blockIdx.x * 256 + wave * 32;
    const float* cnormp = wsf + K;
    const bool smallK = (K <= 1024);

    for (int i = tid; i < 1024; i += 512) hist[i] = 0;

    bf16x8 bf0[2], bf1[2];
    #pragma unroll
    for (int g = 0; g < 2; ++g) {
        int tok = wtok0 + g * 16 + col;
        if (tok >= NT) tok = NT - 1;
        const float* zp = z + (size_t)tok * 64 + quad * 8;
        float4v f0 = *(const float4v*)(zp);
        float4v f1 = *(const float4v*)(zp + 4);
        float4v f2 = *(const float4v*)(zp + 32);
        float4v f3 = *(const float4v*)(zp + 36);
        bf0[g] = cvt8(f0, f1);
        bf1[g] = cvt8(f2, f3);
    }

    unsigned k1[2] = { 0u, 0u }, k2[2] = { 0u, 0u };
    const unsigned kmask = 0xFFFFFF00u;
    const int nchunk = (K + KCH - 1) / KCH;

    for (int c = 0; c < nchunk; ++c) {
        #pragma unroll
        for (int i = 0; i < 4; ++i) {             // KCH*64/512 = 16 floats/thr
            int f4 = (i * 512 + tid) * 4;
            int row = f4 >> 6, d = f4 & 63;
            int code = c * KCH + row;
            uint2 p;
            if (code < K) {
                float4v v = *(const float4v*)(cb + (size_t)code * 64 + d);
                p.x = (unsigned int)bfbits(v[0]) | ((unsigned int)bfbits(v[1]) << 16);
                p.y = (unsigned int)bfbits(v[2]) | ((unsigned int)bfbits(v[3]) << 16);
            } else { p.x = 0u; p.y = 0u; }
            *(uint2*)(&cbs[row * 72 + d]) = p;
        }
        if (tid < KCH) {
            int code = c * KCH + tid;
            cns[tid] = (code < K) ? cnormp[code] : 0.0f;
        }
        __syncthreads();

        #pragma unroll 4
        for (int t = 0; t < KCH / 16; ++t) {
            const unsigned short* arow = cbs + (t * 16 + col) * 72;
            bf16x8 a0 = *(const bf16x8*)(arow + quad * 8);
            bf16x8 a1 = *(const bf16x8*)(arow + 32 + quad * 8);
            float4v cni = *(const float4v*)(cns + t * 16 + quad * 4);
            const int iterbase = ((c * (KCH / 16) + t) << 2);
            #pragma unroll
            for (int g = 0; g < 2; ++g) {
                float4v acc = cni;              // = BIAS - |c|^2/2
                acc = __builtin_amdgcn_mfma_f32_16x16x32_bf16(a0, bf0[g], acc, 0, 0, 0);
                acc = __builtin_amdgcn_mfma_f32_16x16x32_bf16(a1, bf1[g], acc, 0, 0, 0);
                #pragma unroll
                for (int r = 0; r < 4; ++r) {
                    unsigned kb = (__float_as_uint(acc[r]) & kmask) | (unsigned)(iterbase + r);
                    unsigned lo = k2[g] > kb ? k2[g] : kb;
                    k2[g] = k1[g] < lo ? k1[g] : lo;
                    k1[g] = k1[g] > kb ? k1[g] : kb;
                }
            }
        }
        __syncthreads();
    }

    // Cooperative exact refine (R9): 4 quad-lanes per token jointly rerank the
    // token's 8 candidates in fp64; each lane covers a 16-dim slice.
    int ibst[2];
    #pragma unroll
    for (int g = 0; g < 2; ++g) {
        int tok = wtok0 + g * 16 + col;
        if (tok >= NT) tok = NT - 1;
        int ia = dec_idx(k1[g], quad);
        int ib = dec_idx(k2[g], quad);
        int cand[8];
        #pragma unroll
        for (int q = 0; q < 4; ++q) {
            cand[2 * q]     = __shfl(ia, q * 16 + col, 64);
            cand[2 * q + 1] = __shfl(ib, q * 16 + col, 64);
        }
        const float* zr = z + (size_t)tok * 64 + quad * 16;
        float4v zv0 = *(const float4v*)(zr);
        float4v zv1 = *(const float4v*)(zr + 4);
        float4v zv2 = *(const float4v*)(zr + 8);
        float4v zv3 = *(const float4v*)(zr + 12);
        double ps[8];
        #pragma unroll
        for (int s = 0; s < 8; ++s) {
            int cc = (cand[s] < K) ? cand[s] : 0;
            const float* cr = cb + (size_t)cc * 64 + quad * 16;
            float4v c0 = *(const float4v*)(cr);
            float4v c1 = *(const float4v*)(cr + 4);
            float4v c2 = *(const float4v*)(cr + 8);
            float4v c3 = *(const float4v*)(cr + 12);
            double a = 0.0;
            #pragma unroll
            for (int j = 0; j < 4; ++j) {
                double e0 = (double)zv0[j] - (double)c0[j];
                double e1 = (double)zv1[j] - (double)c1[j];
                double e2 = (double)zv2[j] - (double)c2[j];
                double e3 = (double)zv3[j] - (double)c3[j];
                a = fma(e0, e0, a); a = fma(e1, e1, a);
                a = fma(e2, e2, a); a = fma(e3, e3, a);
            }
            ps[s] = (cand[s] < K) ? a : 1.0e300;
        }
        #pragma unroll
        for (int s = 0; s < 8; ++s) {
            ps[s] += __shfl_xor(ps[s], 16, 64);
            ps[s] += __shfl_xor(ps[s], 32, 64);
        }
        double bs = ps[0]; int bi = cand[0];
        #pragma unroll
        for (int s = 1; s < 8; ++s) {
            if (ps[s] < bs || (ps[s] == bs && cand[s] < bi)) { bs = ps[s]; bi = cand[s]; }
        }
        ibst[g] = bi;
    }

    const size_t off_idx = (size_t)NT * 64;

    if (lane < 32) {
        int tk = wtok0 + lane;
        if (tk < NT) {
            int ib = (lane < 16) ? ibst[0] : ibst[1];
            out[off_idx + tk] = (float)ib;
            if (smallK) atomicAdd(&hist[ib], 1);
            else        atomicAdd(&wsi[ib], 1);
        }
    }

    __syncthreads();
    if (smallK) {
        for (int k = tid; k < K; k += 512) {
            int c = hist[k];
            if (c) atomicAdd(&wsi[k], c);
        }
    }
}

// Dimension-partitioned dw scatter + FUSED quantized write / commitment loss.
// Block (chunk, g) owns dims [g*16,+16) of ALL K codes in 64KB LDS and token
// range [chunk*C, +C). Per (token,dim): z load, LDS atomic accumulate, cb
// gather, quantized write, loss slice. Exclusive partial writeout; one loss
// atomic per block. Block 0 folds the nsum duty.
__launch_bounds__(512)
__global__ void vq_dwred(const float* __restrict__ z,
                         const float* __restrict__ cb,
                         const float* __restrict__ out_idx,
                         const float* __restrict__ cs,
                         float* __restrict__ wsf, const int* __restrict__ wsi,
                         float* __restrict__ partial,
                         float* __restrict__ out,
                         int NT, int K, int nchunks) {
    extern __shared__ float acc[];               // K*16 floats
    __shared__ float red[8];

    const int tid   = threadIdx.x;
    const int lane  = tid & 63;
    const int wave  = tid >> 6;                  // 8 waves
    const int chunk = blockIdx.x >> 2;
    const int g     = blockIdx.x & 3;
    const int tsub  = lane >> 4;
    const int d     = lane & 15;
    const size_t KD = (size_t)K * 64;

    for (int i = tid; i < K * 16; i += 512) acc[i] = 0.f;

    if (blockIdx.x == 0) {
        // folded nsum duty (cnt ready: vq_assign completed before this kernel)
        float part = 0.f;
        for (int k = tid; k < K; k += 512)
            part += DECAY * cs[k] + OMD * (float)wsi[k];
        #pragma unroll
        for (int off = 1; off < 64; off <<= 1) part += __shfl_xor(part, off, 64);
        if (lane == 0) red[wave] = part;
        __syncthreads();
        if (tid == 0) {
            float nn = 0.f;
            #pragma unroll
            for (int i = 0; i < 8; ++i) nn += red[i];
            wsf[2 * K + 1] = nn;                                  // n
        }
    }
    __syncthreads();

    const int C  = (NT + nchunks - 1) / nchunks;
    const int T0 = chunk * C;
    const int T1 = (T0 + C < NT) ? (T0 + C) : NT;
    const int doff = g * 16 + d;
    const float* zs = z + doff;

    float lsum = 0.f;
    #pragma unroll 4
    for (int t = T0 + wave * 4 + tsub; t < T1; t += 32) {
        float v   = zs[(size_t)t * 64];
        int  code = (int)out_idx[t];
        float q   = cb[(size_t)code * 64 + doff];
        out[(size_t)t * 64 + doff] = q;
        float e = v - q;
        lsum += e * e;
        atomicAdd(&acc[code * 16 + d], v);
    }
    #pragma unroll
    for (int off = 1; off < 64; off <<= 1) lsum += __shfl_xor(lsum, off, 64);
    __syncthreads();                              // acc complete; red reusable
    if (lane == 0) red[wave] = lsum;
    __syncthreads();
    if (tid == 0) {
        float s = 0.f;
        #pragma unroll
        for (int i = 0; i < 8; ++i) s += red[i];
        atomicAdd(&wsf[2 * K], s);                // loss accumulator
    }

    // exclusive writeout: dims [g*16, g*16+16) of partial[chunk]
    float* pb = partial + (size_t)chunk * KD + g * 16;
    for (int i = tid; i < K * 16; i += 512) {
        int k = i >> 4, dd = i & 15;
        pb[(size_t)k * 64 + dd] = acc[i];
    }
}

// Final: sum chunk partials -> new_ema_w, new_codebook, new_cluster_size.
// 8 independent accumulators -> 8 outstanding loads. Also normalizes loss
// (complete only after vq_dwred now).
__global__ void vq_final(const float* __restrict__ cs,
                         const float* __restrict__ ema,
                         const float* __restrict__ wsf,
                         const int* __restrict__ wsi,
                         const float* __restrict__ partial,
                         float* __restrict__ out, int NT, int K, int S) {
    const int KD = K * 64;
    int t = blockIdx.x * 256 + threadIdx.x;
    if (t == 0) out[(size_t)NT * 64 + NT] = wsf[2 * K] / ((float)NT * 64.0f);
    if (t >= KD) return;
    const int k = t >> 6;
    const float n = wsf[2 * K + 1];
    float d0 = 0.f, d1 = 0.f, d2 = 0.f, d3 = 0.f;
    float d4 = 0.f, d5 = 0.f, d6 = 0.f, d7 = 0.f;
    int s = 0;
    for (; s + 8 <= S; s += 8) {
        d0 += partial[(size_t)(s + 0) * KD + t];
        d1 += partial[(size_t)(s + 1) * KD + t];
        d2 += partial[(size_t)(s + 2) * KD + t];
        d3 += partial[(size_t)(s + 3) * KD + t];
        d4 += partial[(size_t)(s + 4) * KD + t];
        d5 += partial[(size_t)(s + 5) * KD + t];
        d6 += partial[(size_t)(s + 6) * KD + t];
        d7 += partial[(size_t)(s + 7) * KD + t];
    }
    for (; s < S; ++s) d0 += partial[(size_t)s * KD + t];
    const float dsum = ((d0 + d1) + (d2 + d3)) + ((d4 + d5) + (d6 + d7));
    const float dw = DECAY * ema[t] + OMD * dsum;
    const float ncs = DECAY * cs[k] + OMD * (float)wsi[k];
    const float csn = (ncs + EPSV) / (n + (float)K * EPSV) * n;
    const size_t off_cb  = (size_t)NT * 64 + NT + 1;
    const size_t off_cs  = off_cb + (size_t)KD;
    const size_t off_ema = off_cs + K;
    out[off_cb  + t] = dw / csn;
    out[off_ema + t] = dw;
    if ((t & 63) == 0) out[off_cs + k] = ncs;
}

extern "C" void kernel_launch(void* const* d_in, const int* in_sizes, int n_in,
                              void* d_out, int out_size, void* d_ws, size_t ws_size,
                              hipStream_t stream) {
    const float* z   = (const float*)d_in[0];
    const float* cb  = (const float*)d_in[1];
    const float* cs  = (const float*)d_in[2];
    const float* ema = (const float*)d_in[3];
    float* out = (float*)d_out;
    float* wsf = (float*)d_ws;
    int*   wsi = (int*)d_ws;

    const int NT = in_sizes[0] / 64;
    const int K  = in_sizes[2];
    const int KD = K * 64;

    // ws layout (dwords): [0,K) cnt | [K,2K) cnormp | 2K loss | 2K+1 n |
    //   partial[nchunks][K*64]
    size_t avail = ws_size / 4;                  // dwords
    int nchunks = 64;
    while (nchunks > 1 && (size_t)2 * K + 2 + (size_t)nchunks * KD > avail)
        nchunks >>= 1;

    float* partial = wsf + 2 * K + 2;
    const size_t dwlds = (size_t)K * 16 * sizeof(float);   // 64KB @ K=1024

    vq_prep<<<(K + 255) / 256, 256, 0, stream>>>(cb, wsf, wsi, K, NT);
    vq_assign<<<(NT + 255) / 256, 512, 0, stream>>>(z, cb, wsf, wsi, out, NT, K);
    vq_dwred<<<nchunks * 4, 512, dwlds, stream>>>(
        z, cb, out + (size_t)NT * 64, cs, wsf, wsi, partial, out, NT, K, nchunks);
    vq_final<<<(KD + 255) / 256, 256, 0, stream>>>(cs, ema, wsf, wsi, partial,
                                                   out, NT, K, nchunks);
}